// Round 1
// baseline (1209.476 us; speedup 1.0000x reference)
//
#include <hip/hip_runtime.h>

#define NFEAT 128
#define NHID  64
#define NCLS  32

// ---------------- init: deg=1 (self-loop), counters zero ----------------
__global__ void k_init(float* deg, int* cnt, int* cursor, int N) {
    int i = blockIdx.x * blockDim.x + threadIdx.x;
    if (i < N) { deg[i] = 1.0f; cnt[i] = 0; cursor[i] = 0; }
}

// ---------------- per-edge: ew, degree accumulation, CSR histogram ------
__global__ void k_edge_deg(const int* __restrict__ colv, const float* __restrict__ A0,
                           const float* __restrict__ A1, const float* __restrict__ wsv,
                           float* deg, int* cnt, int E) {
    int e = blockIdx.x * blockDim.x + threadIdx.x;
    if (e >= E) return;
    float ew = wsv[0] * A0[e] + wsv[1] * A1[e];
    int c = colv[e];
    atomicAdd(&deg[c], ew);
    atomicAdd(&cnt[c], 1);
}

// ---------------- dinv in place (deg >= 1 always: self-loop weight 1) ---
__global__ void k_dinv(float* deg, int N) {
    int i = blockIdx.x * blockDim.x + threadIdx.x;
    if (i < N) deg[i] = rsqrtf(deg[i]);
}

// ---------------- exclusive scan of cnt -> rowptr (3-phase) -------------
// phase 1: per-block (1024 elems) reduction
__global__ void k_scan1(const int* __restrict__ cnt, int* bsum, int N) {
    __shared__ int lds[256];
    int t = threadIdx.x, b = blockIdx.x;
    int base = b * 1024 + t * 4;
    int s = 0;
#pragma unroll
    for (int i = 0; i < 4; i++) { int idx = base + i; if (idx < N) s += cnt[idx]; }
    lds[t] = s; __syncthreads();
    for (int off = 128; off > 0; off >>= 1) { if (t < off) lds[t] += lds[t + off]; __syncthreads(); }
    if (t == 0) bsum[b] = lds[0];
}

// phase 2: single-block exclusive scan of block sums (NB <= 128)
__global__ void k_scan2(int* bsum, int NB) {
    __shared__ int lds[128];
    int t = threadIdx.x;
    int v = (t < NB) ? bsum[t] : 0;
    lds[t] = v; __syncthreads();
    for (int off = 1; off < 128; off <<= 1) {
        int y = (t >= off) ? lds[t - off] : 0;
        __syncthreads();
        lds[t] += y;
        __syncthreads();
    }
    if (t < NB) bsum[t] = lds[t] - v;   // exclusive
}

// phase 3: per-block scan + offset -> rowptr
__global__ void k_scan3(const int* __restrict__ cnt, const int* __restrict__ bsum,
                        int* rowptr, int N, int E) {
    __shared__ int lds[256];
    int t = threadIdx.x, b = blockIdx.x;
    int base = b * 1024 + t * 4;
    int v[4]; int s = 0;
#pragma unroll
    for (int i = 0; i < 4; i++) { int idx = base + i; v[i] = (idx < N) ? cnt[idx] : 0; s += v[i]; }
    lds[t] = s; __syncthreads();
    for (int off = 1; off < 256; off <<= 1) {       // inclusive scan
        int y = (t >= off) ? lds[t - off] : 0;
        __syncthreads();
        lds[t] += y;
        __syncthreads();
    }
    int run = lds[t] - s + bsum[b];                 // exclusive prefix for this thread
#pragma unroll
    for (int i = 0; i < 4; i++) { int idx = base + i; if (idx < N) rowptr[idx] = run; run += v[i]; }
    if (b == 0 && t == 0) rowptr[N] = E;
}

// ---------------- CSR fill: bucket edges by target, store src + norm ----
__global__ void k_fill(const int* __restrict__ rowv, const int* __restrict__ colv,
                       const float* __restrict__ A0, const float* __restrict__ A1,
                       const float* __restrict__ wsv, const float* __restrict__ dinv,
                       const int* __restrict__ rowptr, int* cursor,
                       int* csr_src, float* csr_w, int E) {
    int e = blockIdx.x * blockDim.x + threadIdx.x;
    if (e >= E) return;
    int r = rowv[e], c = colv[e];
    float ew = wsv[0] * A0[e] + wsv[1] * A1[e];
    int pos = rowptr[c] + atomicAdd(&cursor[c], 1);
    csr_src[pos] = r;
    csr_w[pos] = dinv[r] * ew * dinv[c];
}

// ---------------- GEMM1: h0 = x @ W1  (N x 128) @ (128 x 64) ------------
__global__ __launch_bounds__(256) void k_gemm1(const float* __restrict__ x,
                                               const float* __restrict__ W1,
                                               float* __restrict__ h0, int N) {
    __shared__ float w[NFEAT * NHID];   // 32 KB
    int t = threadIdx.x;
    const float4* W4 = (const float4*)W1;
    float4* w4 = (float4*)w;
#pragma unroll
    for (int i = 0; i < 8; i++) w4[t + 256 * i] = W4[t + 256 * i];
    __syncthreads();
    int wave = t >> 6, lane = t & 63;
    int r0 = blockIdx.x * 32 + wave * 8;
    for (int i = 0; i < 8; i++) {
        int r = r0 + i;
        if (r >= N) break;
        const float4* xr = (const float4*)(x + (size_t)r * NFEAT);
        float acc = 0.f;
#pragma unroll
        for (int k4 = 0; k4 < 32; k4++) {
            float4 xv = xr[k4];
            int k = k4 * 4;
            acc = fmaf(xv.x, w[(k + 0) * 64 + lane], acc);
            acc = fmaf(xv.y, w[(k + 1) * 64 + lane], acc);
            acc = fmaf(xv.z, w[(k + 2) * 64 + lane], acc);
            acc = fmaf(xv.w, w[(k + 3) * 64 + lane], acc);
        }
        h0[(size_t)r * 64 + lane] = acc;
    }
}

// ---------------- aggregate layer 1: wave per node, 64 lanes = 64 feats -
__global__ __launch_bounds__(256) void k_agg1(const float* __restrict__ h0,
                                              const int* __restrict__ rowptr,
                                              const int* __restrict__ csr_src,
                                              const float* __restrict__ csr_w,
                                              const float* __restrict__ dinv,
                                              const float* __restrict__ b1,
                                              float* __restrict__ h, int N) {
    int gid = blockIdx.x * blockDim.x + threadIdx.x;
    int n = gid >> 6;
    int lane = gid & 63;
    if (n >= N) return;
    float di = dinv[n];
    float acc = di * di * h0[(size_t)n * 64 + lane];    // self-loop term
    int e0 = rowptr[n], e1 = rowptr[n + 1];
    for (int e = e0; e < e1; ++e) {
        acc = fmaf(csr_w[e], h0[(size_t)csr_src[e] * 64 + lane], acc);
    }
    float v = acc + b1[lane];
    h[(size_t)n * 64 + lane] = v > 0.f ? v : 0.f;       // relu
}

// ---------------- GEMM2: h2 = h @ W2  (N x 64) @ (64 x 32) --------------
__global__ __launch_bounds__(256) void k_gemm2(const float* __restrict__ h,
                                               const float* __restrict__ W2,
                                               float* __restrict__ h2, int N) {
    __shared__ float w[NHID * NCLS];    // 8 KB
    int t = threadIdx.x;
    const float4* W4 = (const float4*)W2;
    float4* w4 = (float4*)w;
    w4[t] = W4[t];
    if (t < 256) w4[t + 256] = W4[t + 256];
    __syncthreads();
    int wave = t >> 6, lane = t & 63;
    int rsub = lane >> 5, j = lane & 31;
    int r0 = blockIdx.x * 64 + wave * 16 + rsub;
    for (int i = 0; i < 8; i++) {
        int r = r0 + i * 2;
        if (r >= N) continue;
        const float4* hr = (const float4*)(h + (size_t)r * 64);
        float acc = 0.f;
#pragma unroll
        for (int k4 = 0; k4 < 16; k4++) {
            float4 hv = hr[k4];
            int k = k4 * 4;
            acc = fmaf(hv.x, w[(k + 0) * 32 + j], acc);
            acc = fmaf(hv.y, w[(k + 1) * 32 + j], acc);
            acc = fmaf(hv.z, w[(k + 2) * 32 + j], acc);
            acc = fmaf(hv.w, w[(k + 3) * 32 + j], acc);
        }
        h2[(size_t)r * 32 + j] = acc;
    }
}

// ---------------- aggregate layer 2: half-wave per node, 32 feats -------
__global__ __launch_bounds__(256) void k_agg2(const float* __restrict__ h2,
                                              const int* __restrict__ rowptr,
                                              const int* __restrict__ csr_src,
                                              const float* __restrict__ csr_w,
                                              const float* __restrict__ dinv,
                                              const float* __restrict__ b2,
                                              float* __restrict__ out, int N) {
    int gid = blockIdx.x * blockDim.x + threadIdx.x;
    int n = gid >> 5;
    int j = gid & 31;
    if (n >= N) return;
    float di = dinv[n];
    float acc = di * di * h2[(size_t)n * 32 + j];
    int e0 = rowptr[n], e1 = rowptr[n + 1];
    for (int e = e0; e < e1; ++e) {
        acc = fmaf(csr_w[e], h2[(size_t)csr_src[e] * 32 + j], acc);
    }
    out[(size_t)n * 32 + j] = acc + b2[j];
}

extern "C" void kernel_launch(void* const* d_in, const int* in_sizes, int n_in,
                              void* d_out, int out_size, void* d_ws, size_t ws_size,
                              hipStream_t stream) {
    const float* x   = (const float*)d_in[0];
    const int*   ei  = (const int*)d_in[1];     // [2, E] int32
    const float* A0  = (const float*)d_in[2];
    const float* A1  = (const float*)d_in[3];
    const float* wsv = (const float*)d_in[4];
    const float* W1  = (const float*)d_in[5];
    const float* b1  = (const float*)d_in[6];
    const float* W2  = (const float*)d_in[7];
    const float* b2  = (const float*)d_in[8];
    float* out = (float*)d_out;

    int N = in_sizes[0] / NFEAT;    // 100000
    int E = in_sizes[1] / 2;        // 3200000
    const int* rowv = ei;           // source
    const int* colv = ei + E;       // target

    // workspace carve-up (~79 MB)
    char* p = (char*)d_ws;
    auto alloc = [&](size_t bytes) -> void* {
        void* q = (void*)p; p += (bytes + 255) & ~(size_t)255; return q;
    };
    float* deg     = (float*)alloc((size_t)N * 4);          // becomes dinv in place
    int*   cnt     = (int*)  alloc((size_t)N * 4);
    int*   cursor  = (int*)  alloc((size_t)N * 4);
    int*   rowptr  = (int*)  alloc((size_t)(N + 1) * 4);
    int*   bsum    = (int*)  alloc(1024 * 4);
    int*   csr_src = (int*)  alloc((size_t)E * 4);
    float* csr_w   = (float*)alloc((size_t)E * 4);
    float* h0      = (float*)alloc((size_t)N * NHID * 4);
    float* h       = (float*)alloc((size_t)N * NHID * 4);
    float* h2      = h0;    // reuse: h0 dead after agg1

    int NB = (N + 1023) / 1024;     // 98 (<=128 required by k_scan2)

    k_init<<<(N + 255) / 256, 256, 0, stream>>>(deg, cnt, cursor, N);
    k_edge_deg<<<(E + 255) / 256, 256, 0, stream>>>(colv, A0, A1, wsv, deg, cnt, E);
    k_dinv<<<(N + 255) / 256, 256, 0, stream>>>(deg, N);
    k_scan1<<<NB, 256, 0, stream>>>(cnt, bsum, N);
    k_scan2<<<1, 128, 0, stream>>>(bsum, NB);
    k_scan3<<<NB, 256, 0, stream>>>(cnt, bsum, rowptr, N, E);
    k_fill<<<(E + 255) / 256, 256, 0, stream>>>(rowv, colv, A0, A1, wsv, deg,
                                                rowptr, cursor, csr_src, csr_w, E);
    k_gemm1<<<(N + 31) / 32, 256, 0, stream>>>(x, W1, h0, N);
    k_agg1<<<(int)(((size_t)N * 64 + 255) / 256), 256, 0, stream>>>(
        h0, rowptr, csr_src, csr_w, deg, b1, h, N);
    k_gemm2<<<(N + 63) / 64, 256, 0, stream>>>(h, W2, h2, N);
    k_agg2<<<(int)(((size_t)N * 32 + 255) / 256), 256, 0, stream>>>(
        h2, rowptr, csr_src, csr_w, deg, b2, out, N);
}

// Round 2
// 1099.140 us; speedup vs baseline: 1.1004x; 1.1004x over previous
//
#include <hip/hip_runtime.h>

#define NFEAT 128
#define NHID  64
#define NCLS  32

// ---------------- init: deg=1 (self-loop), counters zero ----------------
__global__ void k_init(float* deg, int* cnt, int* cursor, int N) {
    int i = blockIdx.x * blockDim.x + threadIdx.x;
    if (i < N) { deg[i] = 1.0f; cnt[i] = 0; cursor[i] = 0; }
}

// ---------------- per-edge: ew, degree accumulation, CSR histogram ------
__global__ void k_edge_deg(const int* __restrict__ colv, const float* __restrict__ A0,
                           const float* __restrict__ A1, const float* __restrict__ wsv,
                           float* deg, int* cnt, int E) {
    int e = blockIdx.x * blockDim.x + threadIdx.x;
    if (e >= E) return;
    float ew = wsv[0] * A0[e] + wsv[1] * A1[e];
    int c = colv[e];
    atomicAdd(&deg[c], ew);
    atomicAdd(&cnt[c], 1);
}

// ---------------- dinv in place (deg >= 1 always: self-loop weight 1) ---
__global__ void k_dinv(float* deg, int N) {
    int i = blockIdx.x * blockDim.x + threadIdx.x;
    if (i < N) deg[i] = rsqrtf(deg[i]);
}

// ---------------- exclusive scan of cnt -> rowptr (3-phase) -------------
__global__ void k_scan1(const int* __restrict__ cnt, int* bsum, int N) {
    __shared__ int lds[256];
    int t = threadIdx.x, b = blockIdx.x;
    int base = b * 1024 + t * 4;
    int s = 0;
#pragma unroll
    for (int i = 0; i < 4; i++) { int idx = base + i; if (idx < N) s += cnt[idx]; }
    lds[t] = s; __syncthreads();
    for (int off = 128; off > 0; off >>= 1) { if (t < off) lds[t] += lds[t + off]; __syncthreads(); }
    if (t == 0) bsum[b] = lds[0];
}

__global__ void k_scan2(int* bsum, int NB) {
    __shared__ int lds[128];
    int t = threadIdx.x;
    int v = (t < NB) ? bsum[t] : 0;
    lds[t] = v; __syncthreads();
    for (int off = 1; off < 128; off <<= 1) {
        int y = (t >= off) ? lds[t - off] : 0;
        __syncthreads();
        lds[t] += y;
        __syncthreads();
    }
    if (t < NB) bsum[t] = lds[t] - v;   // exclusive
}

__global__ void k_scan3(const int* __restrict__ cnt, const int* __restrict__ bsum,
                        int* rowptr, int N, int E) {
    __shared__ int lds[256];
    int t = threadIdx.x, b = blockIdx.x;
    int base = b * 1024 + t * 4;
    int v[4]; int s = 0;
#pragma unroll
    for (int i = 0; i < 4; i++) { int idx = base + i; v[i] = (idx < N) ? cnt[idx] : 0; s += v[i]; }
    lds[t] = s; __syncthreads();
    for (int off = 1; off < 256; off <<= 1) {
        int y = (t >= off) ? lds[t - off] : 0;
        __syncthreads();
        lds[t] += y;
        __syncthreads();
    }
    int run = lds[t] - s + bsum[b];
#pragma unroll
    for (int i = 0; i < 4; i++) { int idx = base + i; if (idx < N) rowptr[idx] = run; run += v[i]; }
    if (b == 0 && t == 0) rowptr[N] = E;
}

// ---------------- CSR fill: csr_w = ew * dinv[src]; dinv[col] factored --
__global__ void k_fill(const int* __restrict__ rowv, const int* __restrict__ colv,
                       const float* __restrict__ A0, const float* __restrict__ A1,
                       const float* __restrict__ wsv, const float* __restrict__ dinv,
                       const int* __restrict__ rowptr, int* cursor,
                       int* csr_src, float* csr_w, int E) {
    int e = blockIdx.x * blockDim.x + threadIdx.x;
    if (e >= E) return;
    int r = rowv[e], c = colv[e];
    float ew = wsv[0] * A0[e] + wsv[1] * A1[e];
    int pos = rowptr[c] + atomicAdd(&cursor[c], 1);
    csr_src[pos] = r;
    csr_w[pos] = ew * dinv[r];
}

// ---------------- GEMM1: h0 = x @ W1  (N x 128) @ (128 x 64) ------------
__global__ __launch_bounds__(256) void k_gemm1(const float* __restrict__ x,
                                               const float* __restrict__ W1,
                                               float* __restrict__ h0, int N) {
    __shared__ float w[NFEAT * NHID];   // 32 KB
    int t = threadIdx.x;
    const float4* W4 = (const float4*)W1;
    float4* w4 = (float4*)w;
#pragma unroll
    for (int i = 0; i < 8; i++) w4[t + 256 * i] = W4[t + 256 * i];
    __syncthreads();
    int wave = t >> 6, lane = t & 63;
    int r0 = blockIdx.x * 32 + wave * 8;
    for (int i = 0; i < 8; i++) {
        int r = r0 + i;
        if (r >= N) break;
        const float4* xr = (const float4*)(x + (size_t)r * NFEAT);
        float acc = 0.f;
#pragma unroll
        for (int k4 = 0; k4 < 32; k4++) {
            float4 xv = xr[k4];
            int k = k4 * 4;
            acc = fmaf(xv.x, w[(k + 0) * 64 + lane], acc);
            acc = fmaf(xv.y, w[(k + 1) * 64 + lane], acc);
            acc = fmaf(xv.z, w[(k + 2) * 64 + lane], acc);
            acc = fmaf(xv.w, w[(k + 3) * 64 + lane], acc);
        }
        h0[(size_t)r * 64 + lane] = acc;
    }
}

// ---- agg1 + relu + fused GEMM2: h2 = relu(Agg(h0)+b1) @ W2 -------------
// wave per node (grid-stride). lanes: g = lane>>4 edge-group (4 edges in
// flight), l = lane&15 float4 chunk of the 64-f row. W2 column j=lane&31
// cached in 64 VGPRs. h-row broadcast via compile-time shfl.
__global__ __launch_bounds__(256) void k_agg1(const float* __restrict__ h0,
                                              const int* __restrict__ rowptr,
                                              const int* __restrict__ csr_src,
                                              const float* __restrict__ csr_w,
                                              const float* __restrict__ dinv,
                                              const float* __restrict__ b1,
                                              const float* __restrict__ W2,
                                              float* __restrict__ h2, int N,
                                              int nwaves) {
    int t = threadIdx.x;
    int lane = t & 63;
    int wid = (blockIdx.x * blockDim.x + t) >> 6;
    int g = lane >> 4;
    int l = lane & 15;
    int j = lane & 31;
    float wcol[64];
#pragma unroll
    for (int k = 0; k < 64; k++) wcol[k] = W2[k * NCLS + j];
    float4 bv = ((const float4*)b1)[l];

    for (int n = wid; n < N; n += nwaves) {
        int e0 = rowptr[n], e1 = rowptr[n + 1];
        float di = dinv[n];
        float4 acc = make_float4(0.f, 0.f, 0.f, 0.f);
        for (int e = e0 + g; e < e1; e += 4) {
            int src = csr_src[e];
            float w = csr_w[e];
            float4 v = ((const float4*)(h0 + (size_t)src * NHID))[l];
            acc.x = fmaf(w, v.x, acc.x);
            acc.y = fmaf(w, v.y, acc.y);
            acc.z = fmaf(w, v.z, acc.z);
            acc.w = fmaf(w, v.w, acc.w);
        }
#pragma unroll
        for (int off = 16; off < 64; off <<= 1) {
            acc.x += __shfl_xor(acc.x, off, 64);
            acc.y += __shfl_xor(acc.y, off, 64);
            acc.z += __shfl_xor(acc.z, off, 64);
            acc.w += __shfl_xor(acc.w, off, 64);
        }
        float4 sv = ((const float4*)(h0 + (size_t)n * NHID))[l];
        float dd = di * di;
        float4 hrow;
        hrow.x = fmaxf(fmaf(di, acc.x, fmaf(dd, sv.x, bv.x)), 0.f);
        hrow.y = fmaxf(fmaf(di, acc.y, fmaf(dd, sv.y, bv.y)), 0.f);
        hrow.z = fmaxf(fmaf(di, acc.z, fmaf(dd, sv.z, bv.z)), 0.f);
        hrow.w = fmaxf(fmaf(di, acc.w, fmaf(dd, sv.w, bv.w)), 0.f);
        // fused GEMM2: o_j = sum_k h[k] * W2[k][j]
        float o = 0.f;
#pragma unroll
        for (int k = 0; k < 64; k++) {
            float hk = ((k & 3) == 0) ? hrow.x :
                       ((k & 3) == 1) ? hrow.y :
                       ((k & 3) == 2) ? hrow.z : hrow.w;
            hk = __shfl(hk, k >> 2, 64);
            o = fmaf(hk, wcol[k], o);
        }
        if (lane < 32) h2[(size_t)n * NCLS + j] = o;
    }
}

// ---- agg2: out = dinv*Agg(h2) + dinv^2*h2_self + b2 --------------------
// wave per node: g = lane>>3 edge-group (8 edges in flight), l = lane&7
// float4 chunk of the 32-f row.
__global__ __launch_bounds__(256) void k_agg2(const float* __restrict__ h2,
                                              const int* __restrict__ rowptr,
                                              const int* __restrict__ csr_src,
                                              const float* __restrict__ csr_w,
                                              const float* __restrict__ dinv,
                                              const float* __restrict__ b2,
                                              float* __restrict__ out, int N) {
    int t = threadIdx.x;
    int lane = t & 63;
    int n = blockIdx.x * 4 + (t >> 6);
    if (n >= N) return;
    int g = lane >> 3;
    int l = lane & 7;
    int e0 = rowptr[n], e1 = rowptr[n + 1];
    float di = dinv[n];
    float4 acc = make_float4(0.f, 0.f, 0.f, 0.f);
    for (int e = e0 + g; e < e1; e += 8) {
        int src = csr_src[e];
        float w = csr_w[e];
        float4 v = ((const float4*)(h2 + (size_t)src * NCLS))[l];
        acc.x = fmaf(w, v.x, acc.x);
        acc.y = fmaf(w, v.y, acc.y);
        acc.z = fmaf(w, v.z, acc.z);
        acc.w = fmaf(w, v.w, acc.w);
    }
#pragma unroll
    for (int off = 8; off < 64; off <<= 1) {
        acc.x += __shfl_xor(acc.x, off, 64);
        acc.y += __shfl_xor(acc.y, off, 64);
        acc.z += __shfl_xor(acc.z, off, 64);
        acc.w += __shfl_xor(acc.w, off, 64);
    }
    if (lane < 8) {
        float4 sv = ((const float4*)(h2 + (size_t)n * NCLS))[l];
        float4 bvv = ((const float4*)b2)[l];
        float dd = di * di;
        float4 res;
        res.x = fmaf(di, acc.x, fmaf(dd, sv.x, bvv.x));
        res.y = fmaf(di, acc.y, fmaf(dd, sv.y, bvv.y));
        res.z = fmaf(di, acc.z, fmaf(dd, sv.z, bvv.z));
        res.w = fmaf(di, acc.w, fmaf(dd, sv.w, bvv.w));
        ((float4*)(out + (size_t)n * NCLS))[l] = res;
    }
}

extern "C" void kernel_launch(void* const* d_in, const int* in_sizes, int n_in,
                              void* d_out, int out_size, void* d_ws, size_t ws_size,
                              hipStream_t stream) {
    const float* x   = (const float*)d_in[0];
    const int*   ei  = (const int*)d_in[1];     // [2, E] int32
    const float* A0  = (const float*)d_in[2];
    const float* A1  = (const float*)d_in[3];
    const float* wsv = (const float*)d_in[4];
    const float* W1  = (const float*)d_in[5];
    const float* b1  = (const float*)d_in[6];
    const float* W2  = (const float*)d_in[7];
    const float* b2  = (const float*)d_in[8];
    float* out = (float*)d_out;

    int N = in_sizes[0] / NFEAT;    // 100000
    int E = in_sizes[1] / 2;        // 3200000
    const int* rowv = ei;           // source
    const int* colv = ei + E;       // target

    char* p = (char*)d_ws;
    auto alloc = [&](size_t bytes) -> void* {
        void* q = (void*)p; p += (bytes + 255) & ~(size_t)255; return q;
    };
    float* deg     = (float*)alloc((size_t)N * 4);          // becomes dinv in place
    int*   cnt     = (int*)  alloc((size_t)N * 4);
    int*   cursor  = (int*)  alloc((size_t)N * 4);
    int*   rowptr  = (int*)  alloc((size_t)(N + 1) * 4);
    int*   bsum    = (int*)  alloc(1024 * 4);
    int*   csr_src = (int*)  alloc((size_t)E * 4);
    float* csr_w   = (float*)alloc((size_t)E * 4);
    float* h0      = (float*)alloc((size_t)N * NHID * 4);
    float* h2      = (float*)alloc((size_t)N * NCLS * 4);

    int NB = (N + 1023) / 1024;     // 98 (<=128 required by k_scan2)

    k_init<<<(N + 255) / 256, 256, 0, stream>>>(deg, cnt, cursor, N);
    k_edge_deg<<<(E + 255) / 256, 256, 0, stream>>>(colv, A0, A1, wsv, deg, cnt, E);
    k_dinv<<<(N + 255) / 256, 256, 0, stream>>>(deg, N);
    k_scan1<<<NB, 256, 0, stream>>>(cnt, bsum, N);
    k_scan2<<<1, 128, 0, stream>>>(bsum, NB);
    k_scan3<<<NB, 256, 0, stream>>>(cnt, bsum, rowptr, N, E);
    k_fill<<<(E + 255) / 256, 256, 0, stream>>>(rowv, colv, A0, A1, wsv, deg,
                                                rowptr, cursor, csr_src, csr_w, E);
    k_gemm1<<<(N + 31) / 32, 256, 0, stream>>>(x, W1, h0, N);

    int agg1_blocks = 1024;                       // grid-stride, 4096 waves
    int nwaves = agg1_blocks * 4;
    k_agg1<<<agg1_blocks, 256, 0, stream>>>(h0, rowptr, csr_src, csr_w, deg,
                                            b1, W2, h2, N, nwaves);
    k_agg2<<<(N + 3) / 4, 256, 0, stream>>>(h2, rowptr, csr_src, csr_w, deg,
                                            b2, out, N);
}

// Round 3
// 878.015 us; speedup vs baseline: 1.3775x; 1.2518x over previous
//
#include <hip/hip_runtime.h>

#define NFEAT 128
#define NHID  64
#define NCLS  32

// ---------------- init: deg=1 (self-loop), counters zero ----------------
__global__ void k_init(float* deg, int* cnt, int* cursor, int N) {
    int i = blockIdx.x * blockDim.x + threadIdx.x;
    if (i < N) { deg[i] = 1.0f; cnt[i] = 0; cursor[i] = 0; }
}

// ---------------- per-edge: ew, degree accumulation, CSR histogram ------
__global__ void k_edge_deg(const int* __restrict__ colv, const float* __restrict__ A0,
                           const float* __restrict__ A1, const float* __restrict__ wsv,
                           float* __restrict__ ew_out, float* deg, int* cnt, int E) {
    int e = blockIdx.x * blockDim.x + threadIdx.x;
    if (e >= E) return;
    float ew = wsv[0] * A0[e] + wsv[1] * A1[e];
    ew_out[e] = ew;
    int c = colv[e];
    atomicAdd(&deg[c], ew);
    atomicAdd(&cnt[c], 1);
}

// ---------------- dinv in place (deg >= 1 always: self-loop weight 1) ---
__global__ void k_dinv(float* deg, int N) {
    int i = blockIdx.x * blockDim.x + threadIdx.x;
    if (i < N) deg[i] = rsqrtf(deg[i]);
}

// ---------------- exclusive scan of cnt -> rowptr (3-phase) -------------
__global__ void k_scan1(const int* __restrict__ cnt, int* bsum, int N) {
    __shared__ int lds[256];
    int t = threadIdx.x, b = blockIdx.x;
    int base = b * 1024 + t * 4;
    int s = 0;
#pragma unroll
    for (int i = 0; i < 4; i++) { int idx = base + i; if (idx < N) s += cnt[idx]; }
    lds[t] = s; __syncthreads();
    for (int off = 128; off > 0; off >>= 1) { if (t < off) lds[t] += lds[t + off]; __syncthreads(); }
    if (t == 0) bsum[b] = lds[0];
}

__global__ void k_scan2(int* bsum, int NB) {
    __shared__ int lds[128];
    int t = threadIdx.x;
    int v = (t < NB) ? bsum[t] : 0;
    lds[t] = v; __syncthreads();
    for (int off = 1; off < 128; off <<= 1) {
        int y = (t >= off) ? lds[t - off] : 0;
        __syncthreads();
        lds[t] += y;
        __syncthreads();
    }
    if (t < NB) bsum[t] = lds[t] - v;   // exclusive
}

__global__ void k_scan3(const int* __restrict__ cnt, const int* __restrict__ bsum,
                        int* rowptr, int N, int E) {
    __shared__ int lds[256];
    int t = threadIdx.x, b = blockIdx.x;
    int base = b * 1024 + t * 4;
    int v[4]; int s = 0;
#pragma unroll
    for (int i = 0; i < 4; i++) { int idx = base + i; v[i] = (idx < N) ? cnt[idx] : 0; s += v[i]; }
    lds[t] = s; __syncthreads();
    for (int off = 1; off < 256; off <<= 1) {
        int y = (t >= off) ? lds[t - off] : 0;
        __syncthreads();
        lds[t] += y;
        __syncthreads();
    }
    int run = lds[t] - s + bsum[b];
#pragma unroll
    for (int i = 0; i < 4; i++) { int idx = base + i; if (idx < N) rowptr[idx] = run; run += v[i]; }
    if (b == 0 && t == 0) rowptr[N] = E;
}

// ---------------- CSR fill: csr = {src, ew*dinv[src]} packed int2 -------
__global__ void k_fill(const int* __restrict__ rowv, const int* __restrict__ colv,
                       const float* __restrict__ ew_in, const float* __restrict__ dinv,
                       const int* __restrict__ rowptr, int* cursor,
                       int2* __restrict__ csr, int E) {
    int e = blockIdx.x * blockDim.x + threadIdx.x;
    if (e >= E) return;
    int r = rowv[e], c = colv[e];
    float w = ew_in[e] * dinv[r];
    int pos = rowptr[c] + atomicAdd(&cursor[c], 1);
    csr[pos] = make_int2(r, __float_as_int(w));
}

// ---------------- GEMM1: h0 = x @ W1  (N x 128) @ (128 x 64) ------------
__global__ __launch_bounds__(256) void k_gemm1(const float* __restrict__ x,
                                               const float* __restrict__ W1,
                                               float* __restrict__ h0, int N) {
    __shared__ float w[NFEAT * NHID];   // 32 KB
    int t = threadIdx.x;
    const float4* W4 = (const float4*)W1;
    float4* w4 = (float4*)w;
#pragma unroll
    for (int i = 0; i < 8; i++) w4[t + 256 * i] = W4[t + 256 * i];
    __syncthreads();
    int wave = t >> 6, lane = t & 63;
    int r0 = blockIdx.x * 32 + wave * 8;
    for (int i = 0; i < 8; i++) {
        int r = r0 + i;
        if (r >= N) break;
        const float4* xr = (const float4*)(x + (size_t)r * NFEAT);
        float acc = 0.f;
#pragma unroll
        for (int k4 = 0; k4 < 32; k4++) {
            float4 xv = xr[k4];
            int k = k4 * 4;
            acc = fmaf(xv.x, w[(k + 0) * 64 + lane], acc);
            acc = fmaf(xv.y, w[(k + 1) * 64 + lane], acc);
            acc = fmaf(xv.z, w[(k + 2) * 64 + lane], acc);
            acc = fmaf(xv.w, w[(k + 3) * 64 + lane], acc);
        }
        h0[(size_t)r * 64 + lane] = acc;
    }
}

// ---- agg1 + relu: h = relu(dinv*Agg + dinv^2*self + b1) ----------------
// wave per node. g = lane>>4: 4 edges per VMEM instr; l = lane&15: float4
// chunk of the 64-float row. Unroll x2 -> 2 KB outstanding per wave.
__global__ __launch_bounds__(256) void k_agg1(const float* __restrict__ h0,
                                              const int* __restrict__ rowptr,
                                              const int2* __restrict__ csr,
                                              const float* __restrict__ dinv,
                                              const float* __restrict__ b1,
                                              float* __restrict__ h, int N) {
    int t = threadIdx.x;
    int lane = t & 63;
    int n = blockIdx.x * 4 + (t >> 6);
    if (n >= N) return;
    int g = lane >> 4;
    int l = lane & 15;
    int e0 = rowptr[n], e1 = rowptr[n + 1];
    float4 acc0 = make_float4(0.f, 0.f, 0.f, 0.f);
    float4 acc1 = make_float4(0.f, 0.f, 0.f, 0.f);
    int e = e0 + g;
    for (; e + 4 < e1; e += 8) {
        int2 c0 = csr[e];
        int2 c1 = csr[e + 4];
        float4 v0 = ((const float4*)(h0 + (size_t)c0.x * NHID))[l];
        float4 v1 = ((const float4*)(h0 + (size_t)c1.x * NHID))[l];
        float w0 = __int_as_float(c0.y);
        float w1 = __int_as_float(c1.y);
        acc0.x = fmaf(w0, v0.x, acc0.x);
        acc0.y = fmaf(w0, v0.y, acc0.y);
        acc0.z = fmaf(w0, v0.z, acc0.z);
        acc0.w = fmaf(w0, v0.w, acc0.w);
        acc1.x = fmaf(w1, v1.x, acc1.x);
        acc1.y = fmaf(w1, v1.y, acc1.y);
        acc1.z = fmaf(w1, v1.z, acc1.z);
        acc1.w = fmaf(w1, v1.w, acc1.w);
    }
    if (e < e1) {
        int2 c0 = csr[e];
        float4 v0 = ((const float4*)(h0 + (size_t)c0.x * NHID))[l];
        float w0 = __int_as_float(c0.y);
        acc0.x = fmaf(w0, v0.x, acc0.x);
        acc0.y = fmaf(w0, v0.y, acc0.y);
        acc0.z = fmaf(w0, v0.z, acc0.z);
        acc0.w = fmaf(w0, v0.w, acc0.w);
    }
    acc0.x += acc1.x; acc0.y += acc1.y; acc0.z += acc1.z; acc0.w += acc1.w;
#pragma unroll
    for (int off = 16; off < 64; off <<= 1) {
        acc0.x += __shfl_xor(acc0.x, off, 64);
        acc0.y += __shfl_xor(acc0.y, off, 64);
        acc0.z += __shfl_xor(acc0.z, off, 64);
        acc0.w += __shfl_xor(acc0.w, off, 64);
    }
    if (lane < 16) {
        float di = dinv[n];
        float dd = di * di;
        float4 sv = ((const float4*)(h0 + (size_t)n * NHID))[l];
        float4 bv = ((const float4*)b1)[l];
        float4 r;
        r.x = fmaxf(fmaf(di, acc0.x, fmaf(dd, sv.x, bv.x)), 0.f);
        r.y = fmaxf(fmaf(di, acc0.y, fmaf(dd, sv.y, bv.y)), 0.f);
        r.z = fmaxf(fmaf(di, acc0.z, fmaf(dd, sv.z, bv.z)), 0.f);
        r.w = fmaxf(fmaf(di, acc0.w, fmaf(dd, sv.w, bv.w)), 0.f);
        ((float4*)(h + (size_t)n * NHID))[l] = r;
    }
}

// ---------------- GEMM2: h2 = h @ W2  (N x 64) @ (64 x 32) --------------
__global__ __launch_bounds__(256) void k_gemm2(const float* __restrict__ h,
                                               const float* __restrict__ W2,
                                               float* __restrict__ h2, int N) {
    __shared__ float w[NHID * NCLS];    // 8 KB
    int t = threadIdx.x;
    const float4* W4 = (const float4*)W2;
    float4* w4 = (float4*)w;
    w4[t] = W4[t];
    if (t < 256) w4[t + 256] = W4[t + 256];
    __syncthreads();
    int wave = t >> 6, lane = t & 63;
    int rsub = lane >> 5, j = lane & 31;
    int r0 = blockIdx.x * 64 + wave * 16 + rsub;
    for (int i = 0; i < 8; i++) {
        int r = r0 + i * 2;
        if (r >= N) continue;
        const float4* hr = (const float4*)(h + (size_t)r * 64);
        float acc = 0.f;
#pragma unroll
        for (int k4 = 0; k4 < 16; k4++) {
            float4 hv = hr[k4];
            int k = k4 * 4;
            acc = fmaf(hv.x, w[(k + 0) * 32 + j], acc);
            acc = fmaf(hv.y, w[(k + 1) * 32 + j], acc);
            acc = fmaf(hv.z, w[(k + 2) * 32 + j], acc);
            acc = fmaf(hv.w, w[(k + 3) * 32 + j], acc);
        }
        h2[(size_t)r * 32 + j] = acc;
    }
}

// ---- agg2: out = dinv*Agg(h2) + dinv^2*h2_self + b2 --------------------
// wave per node. g = lane>>3: 8 edges per VMEM instr; l = lane&7: float4
// chunk of the 32-float row. Unroll x2.
__global__ __launch_bounds__(256) void k_agg2(const float* __restrict__ h2,
                                              const int* __restrict__ rowptr,
                                              const int2* __restrict__ csr,
                                              const float* __restrict__ dinv,
                                              const float* __restrict__ b2,
                                              float* __restrict__ out, int N) {
    int t = threadIdx.x;
    int lane = t & 63;
    int n = blockIdx.x * 4 + (t >> 6);
    if (n >= N) return;
    int g = lane >> 3;
    int l = lane & 7;
    int e0 = rowptr[n], e1 = rowptr[n + 1];
    float4 acc0 = make_float4(0.f, 0.f, 0.f, 0.f);
    float4 acc1 = make_float4(0.f, 0.f, 0.f, 0.f);
    int e = e0 + g;
    for (; e + 8 < e1; e += 16) {
        int2 c0 = csr[e];
        int2 c1 = csr[e + 8];
        float4 v0 = ((const float4*)(h2 + (size_t)c0.x * NCLS))[l];
        float4 v1 = ((const float4*)(h2 + (size_t)c1.x * NCLS))[l];
        float w0 = __int_as_float(c0.y);
        float w1 = __int_as_float(c1.y);
        acc0.x = fmaf(w0, v0.x, acc0.x);
        acc0.y = fmaf(w0, v0.y, acc0.y);
        acc0.z = fmaf(w0, v0.z, acc0.z);
        acc0.w = fmaf(w0, v0.w, acc0.w);
        acc1.x = fmaf(w1, v1.x, acc1.x);
        acc1.y = fmaf(w1, v1.y, acc1.y);
        acc1.z = fmaf(w1, v1.z, acc1.z);
        acc1.w = fmaf(w1, v1.w, acc1.w);
    }
    if (e < e1) {
        int2 c0 = csr[e];
        float4 v0 = ((const float4*)(h2 + (size_t)c0.x * NCLS))[l];
        float w0 = __int_as_float(c0.y);
        acc0.x = fmaf(w0, v0.x, acc0.x);
        acc0.y = fmaf(w0, v0.y, acc0.y);
        acc0.z = fmaf(w0, v0.z, acc0.z);
        acc0.w = fmaf(w0, v0.w, acc0.w);
    }
    acc0.x += acc1.x; acc0.y += acc1.y; acc0.z += acc1.z; acc0.w += acc1.w;
#pragma unroll
    for (int off = 8; off < 64; off <<= 1) {
        acc0.x += __shfl_xor(acc0.x, off, 64);
        acc0.y += __shfl_xor(acc0.y, off, 64);
        acc0.z += __shfl_xor(acc0.z, off, 64);
        acc0.w += __shfl_xor(acc0.w, off, 64);
    }
    if (lane < 8) {
        float di = dinv[n];
        float dd = di * di;
        float4 sv = ((const float4*)(h2 + (size_t)n * NCLS))[l];
        float4 bv = ((const float4*)b2)[l];
        float4 r;
        r.x = fmaf(di, acc0.x, fmaf(dd, sv.x, bv.x));
        r.y = fmaf(di, acc0.y, fmaf(dd, sv.y, bv.y));
        r.z = fmaf(di, acc0.z, fmaf(dd, sv.z, bv.z));
        r.w = fmaf(di, acc0.w, fmaf(dd, sv.w, bv.w));
        ((float4*)(out + (size_t)n * NCLS))[l] = r;
    }
}

extern "C" void kernel_launch(void* const* d_in, const int* in_sizes, int n_in,
                              void* d_out, int out_size, void* d_ws, size_t ws_size,
                              hipStream_t stream) {
    const float* x   = (const float*)d_in[0];
    const int*   ei  = (const int*)d_in[1];     // [2, E] int32
    const float* A0  = (const float*)d_in[2];
    const float* A1  = (const float*)d_in[3];
    const float* wsv = (const float*)d_in[4];
    const float* W1  = (const float*)d_in[5];
    const float* b1  = (const float*)d_in[6];
    const float* W2  = (const float*)d_in[7];
    const float* b2  = (const float*)d_in[8];
    float* out = (float*)d_out;

    int N = in_sizes[0] / NFEAT;    // 100000
    int E = in_sizes[1] / 2;        // 3200000
    const int* rowv = ei;           // source
    const int* colv = ei + E;       // target

    char* p = (char*)d_ws;
    auto alloc = [&](size_t bytes) -> void* {
        void* q = (void*)p; p += (bytes + 255) & ~(size_t)255; return q;
    };
    float* deg     = (float*)alloc((size_t)N * 4);          // becomes dinv in place
    int*   cnt     = (int*)  alloc((size_t)N * 4);
    int*   cursor  = (int*)  alloc((size_t)N * 4);
    int*   rowptr  = (int*)  alloc((size_t)(N + 1) * 4);
    int*   bsum    = (int*)  alloc(1024 * 4);
    float* ew      = (float*)alloc((size_t)E * 4);
    int2*  csr     = (int2*) alloc((size_t)E * 8);
    float* h0      = (float*)alloc((size_t)N * NHID * 4);
    float* h       = (float*)alloc((size_t)N * NHID * 4);
    float* h2      = (float*)alloc((size_t)N * NCLS * 4);

    int NB = (N + 1023) / 1024;     // 98 (<=128 required by k_scan2)

    k_init<<<(N + 255) / 256, 256, 0, stream>>>(deg, cnt, cursor, N);
    k_edge_deg<<<(E + 255) / 256, 256, 0, stream>>>(colv, A0, A1, wsv, ew, deg, cnt, E);
    k_dinv<<<(N + 255) / 256, 256, 0, stream>>>(deg, N);
    k_scan1<<<NB, 256, 0, stream>>>(cnt, bsum, N);
    k_scan2<<<1, 128, 0, stream>>>(bsum, NB);
    k_scan3<<<NB, 256, 0, stream>>>(cnt, bsum, rowptr, N, E);
    k_fill<<<(E + 255) / 256, 256, 0, stream>>>(rowv, colv, ew, deg,
                                                rowptr, cursor, csr, E);
    k_gemm1<<<(N + 31) / 32, 256, 0, stream>>>(x, W1, h0, N);
    k_agg1<<<(N + 3) / 4, 256, 0, stream>>>(h0, rowptr, csr, deg, b1, h, N);
    k_gemm2<<<(N + 63) / 64, 256, 0, stream>>>(h, W2, h2, N);
    k_agg2<<<(N + 3) / 4, 256, 0, stream>>>(h2, rowptr, csr, deg, b2, out, N);
}

// Round 4
// 673.932 us; speedup vs baseline: 1.7947x; 1.3028x over previous
//
#include <hip/hip_runtime.h>

#define NFEAT 128
#define NHID  64
#define NCLS  32

// ---------------- init: cnt = 0 ----------------------------------------
__global__ void k_init(int* cnt, int N) {
    int i = blockIdx.x * blockDim.x + threadIdx.x;
    if (i < N) cnt[i] = 0;
}

// ---- per-edge: ew + ONE atomic -> rank within target bucket ------------
__global__ void k_edge_rank(const int* __restrict__ colv, const float* __restrict__ A0,
                            const float* __restrict__ A1, const float* __restrict__ wsv,
                            float* __restrict__ ew_out, int* __restrict__ rank,
                            int* cnt, int E) {
    int e = blockIdx.x * blockDim.x + threadIdx.x;
    if (e >= E) return;
    ew_out[e] = wsv[0] * A0[e] + wsv[1] * A1[e];
    rank[e] = atomicAdd(&cnt[colv[e]], 1);
}

// ---------------- exclusive scan of cnt -> rowptr (3-phase) -------------
__global__ void k_scan1(const int* __restrict__ cnt, int* bsum, int N) {
    __shared__ int lds[256];
    int t = threadIdx.x, b = blockIdx.x;
    int base = b * 1024 + t * 4;
    int s = 0;
#pragma unroll
    for (int i = 0; i < 4; i++) { int idx = base + i; if (idx < N) s += cnt[idx]; }
    lds[t] = s; __syncthreads();
    for (int off = 128; off > 0; off >>= 1) { if (t < off) lds[t] += lds[t + off]; __syncthreads(); }
    if (t == 0) bsum[b] = lds[0];
}

__global__ void k_scan2(int* bsum, int NB) {
    __shared__ int lds[128];
    int t = threadIdx.x;
    int v = (t < NB) ? bsum[t] : 0;
    lds[t] = v; __syncthreads();
    for (int off = 1; off < 128; off <<= 1) {
        int y = (t >= off) ? lds[t - off] : 0;
        __syncthreads();
        lds[t] += y;
        __syncthreads();
    }
    if (t < NB) bsum[t] = lds[t] - v;   // exclusive
}

__global__ void k_scan3(const int* __restrict__ cnt, const int* __restrict__ bsum,
                        int* rowptr, int N, int E) {
    __shared__ int lds[256];
    int t = threadIdx.x, b = blockIdx.x;
    int base = b * 1024 + t * 4;
    int v[4]; int s = 0;
#pragma unroll
    for (int i = 0; i < 4; i++) { int idx = base + i; v[i] = (idx < N) ? cnt[idx] : 0; s += v[i]; }
    lds[t] = s; __syncthreads();
    for (int off = 1; off < 256; off <<= 1) {
        int y = (t >= off) ? lds[t - off] : 0;
        __syncthreads();
        lds[t] += y;
        __syncthreads();
    }
    int run = lds[t] - s + bsum[b];
#pragma unroll
    for (int i = 0; i < 4; i++) { int idx = base + i; if (idx < N) rowptr[idx] = run; run += v[i]; }
    if (b == 0 && t == 0) rowptr[N] = E;
}

// ---- CSR fill (atomic-free): csr[rowptr[col]+rank] = {src, ew} ---------
__global__ void k_fill(const int* __restrict__ rowv, const int* __restrict__ colv,
                       const float* __restrict__ ew_in, const int* __restrict__ rank,
                       const int* __restrict__ rowptr, int2* __restrict__ csr, int E) {
    int e = blockIdx.x * blockDim.x + threadIdx.x;
    if (e >= E) return;
    int pos = rowptr[colv[e]] + rank[e];
    csr[pos] = make_int2(rowv[e], __float_as_int(ew_in[e]));
}

// ---- dinv[n] = rsqrt(1 + sum of bucket ew) — coalesced gather ----------
__global__ __launch_bounds__(256) void k_deg(const int2* __restrict__ csr,
                                             const int* __restrict__ rowptr,
                                             float* __restrict__ dinv, int N) {
    int t = threadIdx.x;
    int lane = t & 63;
    int n = blockIdx.x * 4 + (t >> 6);
    if (n >= N) return;
    int e0 = rowptr[n], e1 = rowptr[n + 1];
    float s = 0.f;
    for (int e = e0 + lane; e < e1; e += 64) s += __int_as_float(csr[e].y);
#pragma unroll
    for (int off = 1; off < 64; off <<= 1) s += __shfl_xor(s, off, 64);
    if (lane == 0) dinv[n] = rsqrtf(1.0f + s);
}

// ---- GEMM1 + dinv scale: h0' = dinv[r] * (x @ W1) ----------------------
__global__ __launch_bounds__(256) void k_gemm1(const float* __restrict__ x,
                                               const float* __restrict__ W1,
                                               const float* __restrict__ dinv,
                                               float* __restrict__ h0, int N) {
    __shared__ float w[NFEAT * NHID];   // 32 KB
    int t = threadIdx.x;
    const float4* W4 = (const float4*)W1;
    float4* w4 = (float4*)w;
#pragma unroll
    for (int i = 0; i < 8; i++) w4[t + 256 * i] = W4[t + 256 * i];
    __syncthreads();
    int wave = t >> 6, lane = t & 63;
    int r0 = blockIdx.x * 32 + wave * 8;
    for (int i = 0; i < 8; i++) {
        int r = r0 + i;
        if (r >= N) break;
        const float4* xr = (const float4*)(x + (size_t)r * NFEAT);
        float acc = 0.f;
#pragma unroll
        for (int k4 = 0; k4 < 32; k4++) {
            float4 xv = xr[k4];
            int k = k4 * 4;
            acc = fmaf(xv.x, w[(k + 0) * 64 + lane], acc);
            acc = fmaf(xv.y, w[(k + 1) * 64 + lane], acc);
            acc = fmaf(xv.z, w[(k + 2) * 64 + lane], acc);
            acc = fmaf(xv.w, w[(k + 3) * 64 + lane], acc);
        }
        h0[(size_t)r * 64 + lane] = acc * dinv[r];
    }
}

// ---- agg1 + relu: h = relu(di*(Agg + self) + b1), unroll x4 ------------
// wave per node. g = lane>>4: 4 edges per VMEM instr; l = lane&15: float4
// chunk of the 64-float row. 4 independent accumulators.
__global__ __launch_bounds__(256) void k_agg1(const float* __restrict__ h0,
                                              const int* __restrict__ rowptr,
                                              const int2* __restrict__ csr,
                                              const float* __restrict__ dinv,
                                              const float* __restrict__ b1,
                                              float* __restrict__ h, int N) {
    int t = threadIdx.x;
    int lane = t & 63;
    int n = blockIdx.x * 4 + (t >> 6);
    if (n >= N) return;
    int g = lane >> 4;
    int l = lane & 15;
    int e0 = rowptr[n], e1 = rowptr[n + 1];
    float4 a0 = make_float4(0.f, 0.f, 0.f, 0.f);
    float4 a1 = make_float4(0.f, 0.f, 0.f, 0.f);
    float4 a2 = make_float4(0.f, 0.f, 0.f, 0.f);
    float4 a3 = make_float4(0.f, 0.f, 0.f, 0.f);
    int e = e0 + g;
    for (; e + 12 < e1; e += 16) {
        int2 c0 = csr[e];
        int2 c1 = csr[e + 4];
        int2 c2 = csr[e + 8];
        int2 c3 = csr[e + 12];
        float4 v0 = ((const float4*)(h0 + (size_t)c0.x * NHID))[l];
        float4 v1 = ((const float4*)(h0 + (size_t)c1.x * NHID))[l];
        float4 v2 = ((const float4*)(h0 + (size_t)c2.x * NHID))[l];
        float4 v3 = ((const float4*)(h0 + (size_t)c3.x * NHID))[l];
        float w0 = __int_as_float(c0.y), w1 = __int_as_float(c1.y);
        float w2 = __int_as_float(c2.y), w3 = __int_as_float(c3.y);
        a0.x = fmaf(w0, v0.x, a0.x); a0.y = fmaf(w0, v0.y, a0.y);
        a0.z = fmaf(w0, v0.z, a0.z); a0.w = fmaf(w0, v0.w, a0.w);
        a1.x = fmaf(w1, v1.x, a1.x); a1.y = fmaf(w1, v1.y, a1.y);
        a1.z = fmaf(w1, v1.z, a1.z); a1.w = fmaf(w1, v1.w, a1.w);
        a2.x = fmaf(w2, v2.x, a2.x); a2.y = fmaf(w2, v2.y, a2.y);
        a2.z = fmaf(w2, v2.z, a2.z); a2.w = fmaf(w2, v2.w, a2.w);
        a3.x = fmaf(w3, v3.x, a3.x); a3.y = fmaf(w3, v3.y, a3.y);
        a3.z = fmaf(w3, v3.z, a3.z); a3.w = fmaf(w3, v3.w, a3.w);
    }
    for (; e < e1; e += 4) {
        int2 c0 = csr[e];
        float4 v0 = ((const float4*)(h0 + (size_t)c0.x * NHID))[l];
        float w0 = __int_as_float(c0.y);
        a0.x = fmaf(w0, v0.x, a0.x); a0.y = fmaf(w0, v0.y, a0.y);
        a0.z = fmaf(w0, v0.z, a0.z); a0.w = fmaf(w0, v0.w, a0.w);
    }
    a0.x += a1.x + a2.x + a3.x;
    a0.y += a1.y + a2.y + a3.y;
    a0.z += a1.z + a2.z + a3.z;
    a0.w += a1.w + a2.w + a3.w;
#pragma unroll
    for (int off = 16; off < 64; off <<= 1) {
        a0.x += __shfl_xor(a0.x, off, 64);
        a0.y += __shfl_xor(a0.y, off, 64);
        a0.z += __shfl_xor(a0.z, off, 64);
        a0.w += __shfl_xor(a0.w, off, 64);
    }
    if (lane < 16) {
        float di = dinv[n];
        float4 sv = ((const float4*)(h0 + (size_t)n * NHID))[l];
        float4 bv = ((const float4*)b1)[l];
        float4 r;
        r.x = fmaxf(fmaf(di, a0.x + sv.x, bv.x), 0.f);
        r.y = fmaxf(fmaf(di, a0.y + sv.y, bv.y), 0.f);
        r.z = fmaxf(fmaf(di, a0.z + sv.z, bv.z), 0.f);
        r.w = fmaxf(fmaf(di, a0.w + sv.w, bv.w), 0.f);
        ((float4*)(h + (size_t)n * NHID))[l] = r;
    }
}

// ---- GEMM2 + dinv scale: h2' = dinv[r] * (h @ W2) ----------------------
__global__ __launch_bounds__(256) void k_gemm2(const float* __restrict__ h,
                                               const float* __restrict__ W2,
                                               const float* __restrict__ dinv,
                                               float* __restrict__ h2, int N) {
    __shared__ float w[NHID * NCLS];    // 8 KB
    int t = threadIdx.x;
    const float4* W4 = (const float4*)W2;
    float4* w4 = (float4*)w;
    w4[t] = W4[t];
    if (t < 256) w4[t + 256] = W4[t + 256];
    __syncthreads();
    int wave = t >> 6, lane = t & 63;
    int rsub = lane >> 5, j = lane & 31;
    int r0 = blockIdx.x * 64 + wave * 16 + rsub;
    for (int i = 0; i < 8; i++) {
        int r = r0 + i * 2;
        if (r >= N) continue;
        const float4* hr = (const float4*)(h + (size_t)r * 64);
        float acc = 0.f;
#pragma unroll
        for (int k4 = 0; k4 < 16; k4++) {
            float4 hv = hr[k4];
            int k = k4 * 4;
            acc = fmaf(hv.x, w[(k + 0) * 32 + j], acc);
            acc = fmaf(hv.y, w[(k + 1) * 32 + j], acc);
            acc = fmaf(hv.z, w[(k + 2) * 32 + j], acc);
            acc = fmaf(hv.w, w[(k + 3) * 32 + j], acc);
        }
        h2[(size_t)r * 32 + j] = acc * dinv[r];
    }
}

// ---- agg2: out = di*(Agg + self) + b2, unroll x4 -----------------------
// wave per node. g = lane>>3: 8 edges per VMEM instr; l = lane&7.
__global__ __launch_bounds__(256) void k_agg2(const float* __restrict__ h2,
                                              const int* __restrict__ rowptr,
                                              const int2* __restrict__ csr,
                                              const float* __restrict__ dinv,
                                              const float* __restrict__ b2,
                                              float* __restrict__ out, int N) {
    int t = threadIdx.x;
    int lane = t & 63;
    int n = blockIdx.x * 4 + (t >> 6);
    if (n >= N) return;
    int g = lane >> 3;
    int l = lane & 7;
    int e0 = rowptr[n], e1 = rowptr[n + 1];
    float4 a0 = make_float4(0.f, 0.f, 0.f, 0.f);
    float4 a1 = make_float4(0.f, 0.f, 0.f, 0.f);
    float4 a2 = make_float4(0.f, 0.f, 0.f, 0.f);
    float4 a3 = make_float4(0.f, 0.f, 0.f, 0.f);
    int e = e0 + g;
    for (; e + 24 < e1; e += 32) {
        int2 c0 = csr[e];
        int2 c1 = csr[e + 8];
        int2 c2 = csr[e + 16];
        int2 c3 = csr[e + 24];
        float4 v0 = ((const float4*)(h2 + (size_t)c0.x * NCLS))[l];
        float4 v1 = ((const float4*)(h2 + (size_t)c1.x * NCLS))[l];
        float4 v2 = ((const float4*)(h2 + (size_t)c2.x * NCLS))[l];
        float4 v3 = ((const float4*)(h2 + (size_t)c3.x * NCLS))[l];
        float w0 = __int_as_float(c0.y), w1 = __int_as_float(c1.y);
        float w2 = __int_as_float(c2.y), w3 = __int_as_float(c3.y);
        a0.x = fmaf(w0, v0.x, a0.x); a0.y = fmaf(w0, v0.y, a0.y);
        a0.z = fmaf(w0, v0.z, a0.z); a0.w = fmaf(w0, v0.w, a0.w);
        a1.x = fmaf(w1, v1.x, a1.x); a1.y = fmaf(w1, v1.y, a1.y);
        a1.z = fmaf(w1, v1.z, a1.z); a1.w = fmaf(w1, v1.w, a1.w);
        a2.x = fmaf(w2, v2.x, a2.x); a2.y = fmaf(w2, v2.y, a2.y);
        a2.z = fmaf(w2, v2.z, a2.z); a2.w = fmaf(w2, v2.w, a2.w);
        a3.x = fmaf(w3, v3.x, a3.x); a3.y = fmaf(w3, v3.y, a3.y);
        a3.z = fmaf(w3, v3.z, a3.z); a3.w = fmaf(w3, v3.w, a3.w);
    }
    for (; e < e1; e += 8) {
        int2 c0 = csr[e];
        float4 v0 = ((const float4*)(h2 + (size_t)c0.x * NCLS))[l];
        float w0 = __int_as_float(c0.y);
        a0.x = fmaf(w0, v0.x, a0.x); a0.y = fmaf(w0, v0.y, a0.y);
        a0.z = fmaf(w0, v0.z, a0.z); a0.w = fmaf(w0, v0.w, a0.w);
    }
    a0.x += a1.x + a2.x + a3.x;
    a0.y += a1.y + a2.y + a3.y;
    a0.z += a1.z + a2.z + a3.z;
    a0.w += a1.w + a2.w + a3.w;
#pragma unroll
    for (int off = 8; off < 64; off <<= 1) {
        a0.x += __shfl_xor(a0.x, off, 64);
        a0.y += __shfl_xor(a0.y, off, 64);
        a0.z += __shfl_xor(a0.z, off, 64);
        a0.w += __shfl_xor(a0.w, off, 64);
    }
    if (lane < 8) {
        float di = dinv[n];
        float4 sv = ((const float4*)(h2 + (size_t)n * NCLS))[l];
        float4 bv = ((const float4*)b2)[l];
        float4 r;
        r.x = fmaf(di, a0.x + sv.x, bv.x);
        r.y = fmaf(di, a0.y + sv.y, bv.y);
        r.z = fmaf(di, a0.z + sv.z, bv.z);
        r.w = fmaf(di, a0.w + sv.w, bv.w);
        ((float4*)(out + (size_t)n * NCLS))[l] = r;
    }
}

extern "C" void kernel_launch(void* const* d_in, const int* in_sizes, int n_in,
                              void* d_out, int out_size, void* d_ws, size_t ws_size,
                              hipStream_t stream) {
    const float* x   = (const float*)d_in[0];
    const int*   ei  = (const int*)d_in[1];     // [2, E] int32
    const float* A0  = (const float*)d_in[2];
    const float* A1  = (const float*)d_in[3];
    const float* wsv = (const float*)d_in[4];
    const float* W1  = (const float*)d_in[5];
    const float* b1  = (const float*)d_in[6];
    const float* W2  = (const float*)d_in[7];
    const float* b2  = (const float*)d_in[8];
    float* out = (float*)d_out;

    int N = in_sizes[0] / NFEAT;    // 100000
    int E = in_sizes[1] / 2;        // 3200000
    const int* rowv = ei;           // source
    const int* colv = ei + E;       // target

    char* p = (char*)d_ws;
    auto alloc = [&](size_t bytes) -> void* {
        void* q = (void*)p; p += (bytes + 255) & ~(size_t)255; return q;
    };
    float* dinv    = (float*)alloc((size_t)N * 4);
    int*   cnt     = (int*)  alloc((size_t)N * 4);
    int*   rowptr  = (int*)  alloc((size_t)(N + 1) * 4);
    int*   bsum    = (int*)  alloc(1024 * 4);
    float* ew      = (float*)alloc((size_t)E * 4);
    int*   rank    = (int*)  alloc((size_t)E * 4);
    int2*  csr     = (int2*) alloc((size_t)E * 8);
    float* h0      = (float*)alloc((size_t)N * NHID * 4);
    float* h       = (float*)alloc((size_t)N * NHID * 4);
    float* h2      = (float*)alloc((size_t)N * NCLS * 4);

    int NB = (N + 1023) / 1024;     // 98 (<=128 required by k_scan2)

    k_init<<<(N + 255) / 256, 256, 0, stream>>>(cnt, N);
    k_edge_rank<<<(E + 255) / 256, 256, 0, stream>>>(colv, A0, A1, wsv, ew, rank, cnt, E);
    k_scan1<<<NB, 256, 0, stream>>>(cnt, bsum, N);
    k_scan2<<<1, 128, 0, stream>>>(bsum, NB);
    k_scan3<<<NB, 256, 0, stream>>>(cnt, bsum, rowptr, N, E);
    k_fill<<<(E + 255) / 256, 256, 0, stream>>>(rowv, colv, ew, rank, rowptr, csr, E);
    k_deg<<<(N + 3) / 4, 256, 0, stream>>>(csr, rowptr, dinv, N);
    k_gemm1<<<(N + 31) / 32, 256, 0, stream>>>(x, W1, dinv, h0, N);
    k_agg1<<<(N + 3) / 4, 256, 0, stream>>>(h0, rowptr, csr, dinv, b1, h, N);
    k_gemm2<<<(N + 63) / 64, 256, 0, stream>>>(h, W2, dinv, h2, N);
    k_agg2<<<(N + 3) / 4, 256, 0, stream>>>(h2, rowptr, csr, dinv, b2, out, N);
}